// Round 15
// baseline (73.351 us; speedup 1.0000x reference)
//
#include <hip/hip_runtime.h>
#include <cstdint>
#include <cmath>

#define D_DIM 2048
#define E_DIM 64
#define N_TOK 16384
#define K_TOP 8
#define KSTEP 32
#define TSTEPS 16      // k-steps per K-slice = 512 / 32
#define NFRAG 12       // 4 etiles x 3 terms

typedef __attribute__((ext_vector_type(8))) short bf16x8;
typedef __attribute__((ext_vector_type(4))) float f32x4;

// round-to-nearest bf16 3-way split: x = h + m + l + r, |r| ~ 2^-23 |x|
__device__ inline void split3(const f32x4 v0, const f32x4 v1,
                              bf16x8& h, bf16x8& m, bf16x8& l) {
#pragma unroll
  for (int j = 0; j < 8; ++j) {
    const float x = (j < 4) ? v0[j] : v1[j - 4];
    const unsigned u = __builtin_bit_cast(unsigned, x);
    const unsigned rh = (u + 0x7FFFu + ((u >> 16) & 1u)) & 0xFFFF0000u;
    h[j] = (short)(rh >> 16);
    const float r1 = x - __builtin_bit_cast(float, rh);
    const unsigned u1 = __builtin_bit_cast(unsigned, r1);
    const unsigned rm = (u1 + 0x7FFFu + ((u1 >> 16) & 1u)) & 0xFFFF0000u;
    m[j] = (short)(rm >> 16);
    const float r2 = r1 - __builtin_bit_cast(float, rm);
    l[j] = (short)(__builtin_bit_cast(unsigned, r2) >> 16);
  }
}

// Kernel 1: pre-split W into 3-term MFMA B-fragments.
// WF[(kstep*12 + et*3 + term)*64 + lane]; lane holds W[et*16+(l&15)][kstep*32+(l>>4)*8+j]
__global__ void wprep_kernel(const float* __restrict__ W, uint4* __restrict__ WF) {
  const int gid = blockIdx.x * 256 + threadIdx.x;
  const int lane = gid & 63;
  const int et = (gid >> 6) & 3;
  const int ks = gid >> 8;  // 0..63 global k-step
  const int e = et * 16 + (lane & 15);
  const int kg = lane >> 4;
  const float* src = W + (size_t)e * D_DIM + ks * KSTEP + kg * 8;
  const f32x4 a = *(const f32x4*)src;
  const f32x4 b = *(const f32x4*)(src + 4);
  bf16x8 h, m, l;
  split3(a, b, h, m, l);
  const int fbase = (ks * NFRAG + et * 3) * 64 + lane;
  WF[fbase] = __builtin_bit_cast(uint4, h);
  WF[fbase + 64] = __builtin_bit_cast(uint4, m);
  WF[fbase + 128] = __builtin_bit_cast(uint4, l);
}

#define BCV(x) __builtin_bit_cast(bf16x8, x)
#define MM(d, A, B) d = __builtin_amdgcn_mfma_f32_16x16x32_bf16(A, BCV(B), d, 0, 0, 0)

// forced-register global load: block-uniform SGPR base + per-lane VGPR offset + imm
#define GL4(dst, voff, sbase, IMM)                              \
  asm volatile("global_load_dwordx4 %0, %1, %2 offset:" #IMM    \
               : "=v"(dst) : "v"(voff), "s"(sbase) : "memory")

#define SB0 __builtin_amdgcn_sched_barrier(0)
#define WAITV(N) asm volatile("s_waitcnt vmcnt(" #N ")" ::: "memory")
#define FENCE asm volatile("" ::: "memory")
#define BAR __builtin_amdgcn_s_barrier()

// Kernel A: 512 blocks x 4 waves, 3 blocks/CU (12 waves/CU) for burst anti-phasing.
// Block = 128 tokens x K-slice 512. B staged into LDS ring-2 (24 KB) via
// global_load_lds; X in asm ping-pong regs; uniform vmcnt(4) + 1 barrier/step.
__global__ __launch_bounds__(256, 3)
void gemm_partial(const float* __restrict__ X, const uint4* __restrict__ WF,
                  float* __restrict__ Part) {
  __shared__ uint4 ldsB[2][NFRAG][64];  // 24 KB ring

  const int bid = blockIdx.x;   // 512
  const int ks = bid & 3;       // k-slice
  const int mtile = bid >> 2;   // 0..127 : 128-token tile
  const int tid = threadIdx.x;
  const int w = tid >> 6;
  const int l = tid & 63;
  const int col = l & 15;
  const int kg = l >> 4;
  const int tokw = mtile * 128 + w * 32;  // this wave's 32 tokens

  // BLOCK-uniform base (SGPR-provable: blockIdx-derived only)
  const char* sX = (const char*)X + (size_t)(mtile * 128) * 8192 + (size_t)ks * 2048;
  const char* wfB = (const char*)WF + (size_t)ks * TSTEPS * 12288;

  // per-lane 32-bit offsets (VGPR) — wave offset folded in here
  const unsigned vX0 = (unsigned)(w * 32 * 8192 + col * 8192 + kg * 32);
  const unsigned vX1 = vX0 + 16 * 8192;

  f32x4 acc0[8], acc1[8];  // [half*4+et]
#pragma unroll
  for (int i = 0; i < 8; ++i) { acc0[i] = (f32x4)0.f; acc1[i] = (f32x4)0.f; }

  f32x4 xE[4], xO[4];

#define LOADX(xS, t)                          \
  do {                                        \
    const char* sX_ = sX + (size_t)(t) * 128; \
    GL4(xS[0], vX0, sX_, 0);                  \
    GL4(xS[1], vX0, sX_, 16);                 \
    GL4(xS[2], vX1, sX_, 0);                  \
    GL4(xS[3], vX1, sX_, 16);                 \
  } while (0)

  // stage this wave's 3 frags of step t into ring buffer buf (wave-uniform LDS dest)
#define STAGE(t, buf)                                                        \
  do {                                                                       \
    _Pragma("unroll") for (int c = 0; c < 3; ++c) {                          \
      const int f_ = w * 3 + c;                                              \
      const char* g_ = wfB + (size_t)(t) * 12288 + f_ * 1024 + l * 16;       \
      __builtin_amdgcn_global_load_lds(                                      \
          (const __attribute__((address_space(1))) void*)g_,                 \
          (__attribute__((address_space(3))) void*)&ldsB[buf][f_][0], 16, 0, 0); \
    }                                                                        \
  } while (0)

  // 48 MFMAs, phased h/m/l so only 4 B-frags are live at a time (VGPR <=170)
#define CRUNCH(buf, xS)                                                            \
  do {                                                                             \
    bf16x8 ah0, am0, al0, ah1, am1, al1;                                           \
    split3(xS[0], xS[1], ah0, am0, al0);                                           \
    split3(xS[2], xS[3], ah1, am1, al1);                                           \
    const uint4* fb_ = &ldsB[buf][0][0];                                           \
    {                                                                              \
      uint4 hh0 = fb_[0 * 64 + l], hh1 = fb_[3 * 64 + l];                          \
      uint4 hh2 = fb_[6 * 64 + l], hh3 = fb_[9 * 64 + l];                          \
      MM(acc0[0], ah0, hh0); MM(acc0[4], ah1, hh0);                                \
      MM(acc0[1], ah0, hh1); MM(acc0[5], ah1, hh1);                                \
      MM(acc0[2], ah0, hh2); MM(acc0[6], ah1, hh2);                                \
      MM(acc0[3], ah0, hh3); MM(acc0[7], ah1, hh3);                                \
      MM(acc1[0], am0, hh0); MM(acc1[4], am1, hh0);                                \
      MM(acc1[1], am0, hh1); MM(acc1[5], am1, hh1);                                \
      MM(acc1[2], am0, hh2); MM(acc1[6], am1, hh2);                                \
      MM(acc1[3], am0, hh3); MM(acc1[7], am1, hh3);                                \
      MM(acc1[0], al0, hh0); MM(acc1[4], al1, hh0);                                \
      MM(acc1[1], al0, hh1); MM(acc1[5], al1, hh1);                                \
      MM(acc1[2], al0, hh2); MM(acc1[6], al1, hh2);                                \
      MM(acc1[3], al0, hh3); MM(acc1[7], al1, hh3);                                \
    }                                                                              \
    {                                                                              \
      uint4 mm0 = fb_[1 * 64 + l], mm1 = fb_[4 * 64 + l];                          \
      uint4 mm2 = fb_[7 * 64 + l], mm3 = fb_[10 * 64 + l];                         \
      MM(acc1[0], ah0, mm0); MM(acc1[4], ah1, mm0);                                \
      MM(acc1[1], ah0, mm1); MM(acc1[5], ah1, mm1);                                \
      MM(acc1[2], ah0, mm2); MM(acc1[6], ah1, mm2);                                \
      MM(acc1[3], ah0, mm3); MM(acc1[7], ah1, mm3);                                \
      MM(acc1[0], am0, mm0); MM(acc1[4], am1, mm0);                                \
      MM(acc1[1], am0, mm1); MM(acc1[5], am1, mm1);                                \
      MM(acc1[2], am0, mm2); MM(acc1[6], am1, mm2);                                \
      MM(acc1[3], am0, mm3); MM(acc1[7], am1, mm3);                                \
    }                                                                              \
    {                                                                              \
      uint4 ll0 = fb_[2 * 64 + l], ll1 = fb_[5 * 64 + l];                          \
      uint4 ll2 = fb_[8 * 64 + l], ll3 = fb_[11 * 64 + l];                         \
      MM(acc1[0], ah0, ll0); MM(acc1[4], ah1, ll0);                                \
      MM(acc1[1], ah0, ll1); MM(acc1[5], ah1, ll1);                                \
      MM(acc1[2], ah0, ll2); MM(acc1[6], ah1, ll2);                                \
      MM(acc1[3], ah0, ll3); MM(acc1[7], ah1, ll3);                                \
    }                                                                              \
  } while (0)

  // prologue: queue = s0(3), x0(4), x1(4) = 11 outstanding
  STAGE(0, 0);
  LOADX(xE, 0);
  LOADX(xO, 1);

  // steady state: entering step t queue = x(t)(4), s(t)(3), x(t+1)(4);
  // WAITV(4) retires x(t)+s(t); then STAGE(t+1)+3, LOADX(t+2)+4 -> 11 again.
#pragma unroll 1
  for (int t = 0; t < TSTEPS - 2; t += 2) {  // t = 0,2,...,12
    WAITV(4);
    SB0;
    FENCE; BAR; FENCE;           // all waves' stage(t) landed, buf(t-1) reads done
    STAGE(t + 1, (t + 1) & 1);   // safe: buf(t+1)≡buf(t-1) last read before this BAR
    CRUNCH(t & 1, xE);
    LOADX(xE, t + 2);
    WAITV(4);
    SB0;
    FENCE; BAR; FENCE;
    STAGE(t + 2, (t + 2) & 1);
    CRUNCH((t + 1) & 1, xO);
    LOADX(xO, t + 3);
  }
  // t = 14: queue = x14(4), s14(3), x15(4)
  WAITV(4);
  SB0;
  FENCE; BAR; FENCE;
  STAGE(15, 1);
  CRUNCH(0, xE);
  // t = 15: queue = x15(4), s15(3)
  WAITV(0);
  SB0;
  FENCE; BAR; FENCE;
  CRUNCH(1, xO);

  // write partials: Part[ks][tok][e]; C/D layout col=lane&15, row=(lane>>4)*4+q
#pragma unroll
  for (int half = 0; half < 2; ++half)
#pragma unroll
    for (int q = 0; q < 4; ++q) {
      const int tok = tokw + half * 16 + kg * 4 + q;
      float* dst = Part + ((size_t)ks * N_TOK + tok) * E_DIM + col;
#pragma unroll
      for (int et = 0; et < 4; ++et)
        dst[et * 16] = acc0[half * 4 + et][q] + acc1[half * 4 + et][q];
    }
}

// Kernel B: fixed-order 4-way reduce + validated ballot top-8 + softmax + scatter.
__global__ __launch_bounds__(256)
void reduce_router(const float* __restrict__ Part,
                   float* __restrict__ Pout, float* __restrict__ Mout) {
  const int lane = threadIdx.x & 63;
  const int gw = blockIdx.x * 4 + (threadIdx.x >> 6);  // 4096 waves

#pragma unroll 1
  for (int j = 0; j < 4; ++j) {
    const int tok = gw * 4 + j;
    const size_t base = (size_t)tok * E_DIM + lane;
    float v = Part[base];
    v += Part[(size_t)1 * N_TOK * E_DIM + base];
    v += Part[(size_t)2 * N_TOK * E_DIM + base];
    v += Part[(size_t)3 * N_TOK * E_DIM + base];

    float topv[K_TOP];
    int topi[K_TOP];
#pragma unroll
    for (int kk = 0; kk < K_TOP; ++kk) {
      float m = v;
#pragma unroll
      for (int off = 32; off > 0; off >>= 1)
        m = fmaxf(m, __shfl_xor(m, off, 64));
      const unsigned long long bal = __ballot(v == m);
      const int li = __ffsll(bal) - 1;  // lowest expert on ties == jax stable order
      topv[kk] = m;
      topi[kk] = li;
      if (lane == li) v = -INFINITY;
    }

    float p[K_TOP], sum = 0.f;
#pragma unroll
    for (int kk = 0; kk < K_TOP; ++kk) {
      p[kk] = expf(topv[kk] - topv[0]);
      sum += p[kk];
    }
    const float inv = 1.f / sum;

    float pv = 0.f, mv = 0.f;
#pragma unroll
    for (int kk = 0; kk < K_TOP; ++kk)
      if (topi[kk] == lane) { pv = p[kk] * inv; mv = 1.f; }

    Pout[(size_t)tok * E_DIM + lane] = pv;
    Mout[(size_t)tok * E_DIM + lane] = mv;
  }
}

extern "C" void kernel_launch(void* const* d_in, const int* in_sizes, int n_in,
                              void* d_out, int out_size, void* d_ws, size_t ws_size,
                              hipStream_t stream) {
  const float* X = (const float*)d_in[0];
  const float* W = (const float*)d_in[1];
  float* P = (float*)d_out;
  float* M = P + (size_t)N_TOK * E_DIM;

  uint4* WF = (uint4*)d_ws;                                 // 768 KB at offset 0
  float* Part = (float*)((char*)d_ws + (size_t)(1 << 20));  // 16 MB at offset 1 MB

  wprep_kernel<<<dim3(64), dim3(256), 0, stream>>>(W, WF);
  gemm_partial<<<dim3(512), dim3(256), 0, stream>>>(X, WF, Part);
  reduce_router<<<dim3(1024), dim3(256), 0, stream>>>(Part, P, M);
}

// Round 18
// 51.721 us; speedup vs baseline: 1.4182x; 1.4182x over previous
//
#include <hip/hip_runtime.h>
#include <cstdint>
#include <cmath>

#define D_DIM 2048
#define E_DIM 64
#define N_TOK 16384
#define K_TOP 8
#define KSTEP 32
#define NFRAG 12       // 4 etiles x 3 terms

typedef __attribute__((ext_vector_type(8))) short bf16x8;
typedef __attribute__((ext_vector_type(4))) float f32x4;

// round-to-nearest bf16 3-way split: x = h + m + l + r, |r| ~ 2^-23 |x|
__device__ inline void split3(const f32x4 v0, const f32x4 v1,
                              bf16x8& h, bf16x8& m, bf16x8& l) {
#pragma unroll
  for (int j = 0; j < 8; ++j) {
    const float x = (j < 4) ? v0[j] : v1[j - 4];
    const unsigned u = __builtin_bit_cast(unsigned, x);
    const unsigned rh = (u + 0x7FFFu + ((u >> 16) & 1u)) & 0xFFFF0000u;
    h[j] = (short)(rh >> 16);
    const float r1 = x - __builtin_bit_cast(float, rh);
    const unsigned u1 = __builtin_bit_cast(unsigned, r1);
    const unsigned rm = (u1 + 0x7FFFu + ((u1 >> 16) & 1u)) & 0xFFFF0000u;
    m[j] = (short)(rm >> 16);
    const float r2 = r1 - __builtin_bit_cast(float, rm);
    l[j] = (short)(__builtin_bit_cast(unsigned, r2) >> 16);
  }
}

// Kernel 1: pre-split W into 3-term MFMA B-fragments.
__global__ void wprep_kernel(const float* __restrict__ W, uint4* __restrict__ WF) {
  const int gid = blockIdx.x * 256 + threadIdx.x;
  const int lane = gid & 63;
  const int et = (gid >> 6) & 3;
  const int ks = gid >> 8;  // 0..63 global k-step
  const int e = et * 16 + (lane & 15);
  const int kg = lane >> 4;
  const float* src = W + (size_t)e * D_DIM + ks * KSTEP + kg * 8;
  const f32x4 a = *(const f32x4*)src;
  const f32x4 b = *(const f32x4*)(src + 4);
  bf16x8 h, m, l;
  split3(a, b, h, m, l);
  const int fbase = (ks * NFRAG + et * 3) * 64 + lane;
  WF[fbase] = __builtin_bit_cast(uint4, h);
  WF[fbase + 64] = __builtin_bit_cast(uint4, m);
  WF[fbase + 128] = __builtin_bit_cast(uint4, l);
}

#define BCV(x) __builtin_bit_cast(bf16x8, x)
#define MM(d, A, B) d = __builtin_amdgcn_mfma_f32_16x16x32_bf16(A, BCV(B), d, 0, 0, 0)

#define GL4(dst, voff, sbase, IMM)                              \
  asm volatile("global_load_dwordx4 %0, %1, %2 offset:" #IMM    \
               : "=v"(dst) : "v"(voff), "s"(sbase) : "memory")

#define SB0 __builtin_amdgcn_sched_barrier(0)
#define WAITV(N) asm volatile("s_waitcnt vmcnt(" #N ")" ::: "memory")
#define WAITL0 asm volatile("s_waitcnt lgkmcnt(0)" ::: "memory")
#define FENCE asm volatile("" ::: "memory")
#define BAR __builtin_amdgcn_s_barrier()

// Kernel A: 512 blocks x 4 waves. Block = 128 tokens x K-slice 512 (4 phases x
// 4 steps). Phase-B staged: 12 asm GL4 into regs issued one FULL PHASE ahead ->
// ds_write at boundary (2 barriers/phase, 8 total). Steps inside a phase are
// barrier-free. ORDER IS ALWAYS waitv -> CRUNCH(consume) -> LOADX(refill): the
// refill targets the just-consumed registers (r17's WAR race fixed).
__global__ __launch_bounds__(256, 2)
void gemm_partial(const float* __restrict__ X, const uint4* __restrict__ WF,
                  float* __restrict__ Part) {
  __shared__ uint4 ldsB[4][NFRAG][64];  // one phase: 4 steps x 12 frags = 48 KB

  const int bid = blockIdx.x;   // 512
  const int ks = bid & 3;       // k-slice
  const int mtile = bid >> 2;   // 0..127 : 128-token tile
  const int tid = threadIdx.x;
  const int w = tid >> 6;
  const int l = tid & 63;
  const int col = l & 15;
  const int kg = l >> 4;
  const int w3 = w * 3;
  const int tokw = mtile * 128 + w * 32;

  const char* sX = (const char*)X + (size_t)(mtile * 128) * 8192 + (size_t)ks * 2048;
  const char* wfB = (const char*)WF + (size_t)ks * 16 * 12288;  // 16 steps/slice

  const unsigned vX0 = (unsigned)(w * 32 * 8192 + col * 8192 + kg * 32);
  const unsigned vX1 = vX0 + 16 * 8192;
  const unsigned voffB = (unsigned)(w3 * 1024 + l * 16);

  f32x4 acc0[8], acc1[8];
#pragma unroll
  for (int i = 0; i < 8; ++i) { acc0[i] = (f32x4)0.f; acc1[i] = (f32x4)0.f; }

  f32x4 xE[4], xO[4];
  uint4 bP[12];  // phase-B staging regs (asm-forced live)

#define LOADX(xS, g)                          \
  do {                                        \
    const char* sX_ = sX + (size_t)(g) * 128; \
    GL4(xS[0], vX0, sX_, 0);                  \
    GL4(xS[1], vX0, sX_, 16);                 \
    GL4(xS[2], vX1, sX_, 0);                  \
    GL4(xS[3], vX1, sX_, 16);                 \
  } while (0)

#define ISSUE_B(ph)                                            \
  do {                                                         \
    const char* sb_ = wfB + (size_t)(ph) * 49152;              \
    GL4(bP[0], voffB, sb_, 0);                                 \
    GL4(bP[1], voffB, sb_, 1024);                              \
    GL4(bP[2], voffB, sb_, 2048);                              \
    const char* s1_ = sb_ + 12288;                             \
    GL4(bP[3], voffB, s1_, 0);                                 \
    GL4(bP[4], voffB, s1_, 1024);                              \
    GL4(bP[5], voffB, s1_, 2048);                              \
    const char* s2_ = sb_ + 24576;                             \
    GL4(bP[6], voffB, s2_, 0);                                 \
    GL4(bP[7], voffB, s2_, 1024);                              \
    GL4(bP[8], voffB, s2_, 2048);                              \
    const char* s3_ = sb_ + 36864;                             \
    GL4(bP[9], voffB, s3_, 0);                                 \
    GL4(bP[10], voffB, s3_, 1024);                             \
    GL4(bP[11], voffB, s3_, 2048);                             \
  } while (0)

#define DSW                                   \
  do {                                        \
    ldsB[0][w3 + 0][l] = bP[0];               \
    ldsB[0][w3 + 1][l] = bP[1];               \
    ldsB[0][w3 + 2][l] = bP[2];               \
    ldsB[1][w3 + 0][l] = bP[3];               \
    ldsB[1][w3 + 1][l] = bP[4];               \
    ldsB[1][w3 + 2][l] = bP[5];               \
    ldsB[2][w3 + 0][l] = bP[6];               \
    ldsB[2][w3 + 1][l] = bP[7];               \
    ldsB[2][w3 + 2][l] = bP[8];               \
    ldsB[3][w3 + 0][l] = bP[9];               \
    ldsB[3][w3 + 1][l] = bP[10];              \
    ldsB[3][w3 + 2][l] = bP[11];              \
  } while (0)

#define CRUNCH(s, xS)                                                              \
  do {                                                                             \
    bf16x8 ah0, am0, al0, ah1, am1, al1;                                           \
    split3(xS[0], xS[1], ah0, am0, al0);                                           \
    split3(xS[2], xS[3], ah1, am1, al1);                                           \
    const uint4* fb_ = &ldsB[s][0][0];                                             \
    {                                                                              \
      uint4 hh0 = fb_[0 * 64 + l], hh1 = fb_[3 * 64 + l];                          \
      uint4 hh2 = fb_[6 * 64 + l], hh3 = fb_[9 * 64 + l];                          \
      MM(acc0[0], ah0, hh0); MM(acc0[4], ah1, hh0);                                \
      MM(acc0[1], ah0, hh1); MM(acc0[5], ah1, hh1);                                \
      MM(acc0[2], ah0, hh2); MM(acc0[6], ah1, hh2);                                \
      MM(acc0[3], ah0, hh3); MM(acc0[7], ah1, hh3);                                \
      MM(acc1[0], am0, hh0); MM(acc1[4], am1, hh0);                                \
      MM(acc1[1], am0, hh1); MM(acc1[5], am1, hh1);                                \
      MM(acc1[2], am0, hh2); MM(acc1[6], am1, hh2);                                \
      MM(acc1[3], am0, hh3); MM(acc1[7], am1, hh3);                                \
      MM(acc1[0], al0, hh0); MM(acc1[4], al1, hh0);                                \
      MM(acc1[1], al0, hh1); MM(acc1[5], al1, hh1);                                \
      MM(acc1[2], al0, hh2); MM(acc1[6], al1, hh2);                                \
      MM(acc1[3], al0, hh3); MM(acc1[7], al1, hh3);                                \
    }                                                                              \
    {                                                                              \
      uint4 mm0 = fb_[1 * 64 + l], mm1 = fb_[4 * 64 + l];                          \
      uint4 mm2 = fb_[7 * 64 + l], mm3 = fb_[10 * 64 + l];                         \
      MM(acc1[0], ah0, mm0); MM(acc1[4], ah1, mm0);                                \
      MM(acc1[1], ah0, mm1); MM(acc1[5], ah1, mm1);                                \
      MM(acc1[2], ah0, mm2); MM(acc1[6], ah1, mm2);                                \
      MM(acc1[3], ah0, mm3); MM(acc1[7], ah1, mm3);                                \
      MM(acc1[0], am0, mm0); MM(acc1[4], am1, mm0);                                \
      MM(acc1[1], am0, mm1); MM(acc1[5], am1, mm1);                                \
      MM(acc1[2], am0, mm2); MM(acc1[6], am1, mm2);                                \
      MM(acc1[3], am0, mm3); MM(acc1[7], am1, mm3);                                \
    }                                                                              \
    {                                                                              \
      uint4 ll0 = fb_[2 * 64 + l], ll1 = fb_[5 * 64 + l];                          \
      uint4 ll2 = fb_[8 * 64 + l], ll3 = fb_[11 * 64 + l];                         \
      MM(acc1[0], ah0, ll0); MM(acc1[4], ah1, ll0);                                \
      MM(acc1[1], ah0, ll1); MM(acc1[5], ah1, ll1);                                \
      MM(acc1[2], ah0, ll2); MM(acc1[6], ah1, ll2);                                \
      MM(acc1[3], ah0, ll3); MM(acc1[7], ah1, ll3);                                \
    }                                                                              \
  } while (0)

  // prologue: B(0) 12 + X0 4 + X1 4 = 20 outstanding
  ISSUE_B(0);
  LOADX(xE, 0);
  LOADX(xO, 1);

#pragma unroll 1
  for (int p = 0; p < 3; ++p) {  // phases 0..2 (phase 3 = tail)
    const int g0 = p * 4;
    FENCE; BAR; FENCE;           // all waves done reading previous phase LDS
    WAITV(8); SB0;               // retire B(p) regs; X(g0),X(g0+1) remain
    DSW;
    WAITL0; SB0;
    FENCE; BAR; FENCE;           // phase buffer ready for all waves
    ISSUE_B(p + 1);              // queue: X(g0)4, X(g0+1)4, B(p+1)12 = 20
    // q0: consume X(g0), refill xE with X(g0+2)
    WAITV(16); SB0;              // retire X(g0)
    CRUNCH(0, xE);
    LOADX(xE, g0 + 2);           // queue: X(g0+1)4, B(p+1)12, X(g0+2)4 = 20
    // q1: consume X(g0+1), refill xO with X(g0+3)
    WAITV(16); SB0;              // retire X(g0+1)
    CRUNCH(1, xO);
    LOADX(xO, g0 + 3);           // queue: B(p+1)12, X(g0+2)4, X(g0+3)4 = 20
    // q2: consume X(g0+2) (retires B(p+1) first, in-order)
    WAITV(4); SB0;               // retire B(p+1) + X(g0+2)
    CRUNCH(2, xE);
    LOADX(xE, g0 + 4);           // queue: X(g0+3)4, X(g0+4)4 = 8
    // q3: consume X(g0+3)
    WAITV(4); SB0;               // retire X(g0+3)
    CRUNCH(3, xO);
    LOADX(xO, g0 + 5);           // queue: X(g0+4)4, X(g0+5)4 = 8
  }
  // phase 3 tail (steps 12..15); B(3) regs landed (retired at p=2 q2)
  FENCE; BAR; FENCE;
  WAITV(8); SB0;                 // no-op (8 outstanding), keeps ledger explicit
  DSW;
  WAITL0; SB0;
  FENCE; BAR; FENCE;
  WAITV(4); SB0;                 // retire X12
  CRUNCH(0, xE);
  LOADX(xE, 14);                 // queue: X13 4, X14 4 = 8
  WAITV(4); SB0;                 // retire X13
  CRUNCH(1, xO);
  LOADX(xO, 15);                 // queue: X14 4, X15 4 = 8
  WAITV(4); SB0;                 // retire X14
  CRUNCH(2, xE);
  WAITV(0); SB0;                 // retire X15
  CRUNCH(3, xO);

  // write partials: Part[ks][tok][e]; C/D layout col=lane&15, row=(lane>>4)*4+q
#pragma unroll
  for (int half = 0; half < 2; ++half)
#pragma unroll
    for (int q = 0; q < 4; ++q) {
      const int tok = tokw + half * 16 + kg * 4 + q;
      float* dst = Part + ((size_t)ks * N_TOK + tok) * E_DIM + col;
#pragma unroll
      for (int et = 0; et < 4; ++et)
        dst[et * 16] = acc0[half * 4 + et][q] + acc1[half * 4 + et][q];
    }
}

// Kernel B: fixed-order 4-way reduce + validated ballot top-8 + softmax + scatter.
__global__ __launch_bounds__(256)
void reduce_router(const float* __restrict__ Part,
                   float* __restrict__ Pout, float* __restrict__ Mout) {
  const int lane = threadIdx.x & 63;
  const int gw = blockIdx.x * 4 + (threadIdx.x >> 6);  // 4096 waves

#pragma unroll 1
  for (int j = 0; j < 4; ++j) {
    const int tok = gw * 4 + j;
    const size_t base = (size_t)tok * E_DIM + lane;
    float v = Part[base];
    v += Part[(size_t)1 * N_TOK * E_DIM + base];
    v += Part[(size_t)2 * N_TOK * E_DIM + base];
    v += Part[(size_t)3 * N_TOK * E_DIM + base];

    float topv[K_TOP];
    int topi[K_TOP];
#pragma unroll
    for (int kk = 0; kk < K_TOP; ++kk) {
      float m = v;
#pragma unroll
      for (int off = 32; off > 0; off >>= 1)
        m = fmaxf(m, __shfl_xor(m, off, 64));
      const unsigned long long bal = __ballot(v == m);
      const int li = __ffsll(bal) - 1;  // lowest expert on ties == jax stable order
      topv[kk] = m;
      topi[kk] = li;
      if (lane == li) v = -INFINITY;
    }

    float p[K_TOP], sum = 0.f;
#pragma unroll
    for (int kk = 0; kk < K_TOP; ++kk) {
      p[kk] = expf(topv[kk] - topv[0]);
      sum += p[kk];
    }
    const float inv = 1.f / sum;

    float pv = 0.f, mv = 0.f;
#pragma unroll
    for (int kk = 0; kk < K_TOP; ++kk)
      if (topi[kk] == lane) { pv = p[kk] * inv; mv = 1.f; }

    Pout[(size_t)tok * E_DIM + lane] = pv;
    Mout[(size_t)tok * E_DIM + lane] = mv;
  }
}

extern "C" void kernel_launch(void* const* d_in, const int* in_sizes, int n_in,
                              void* d_out, int out_size, void* d_ws, size_t ws_size,
                              hipStream_t stream) {
  const float* X = (const float*)d_in[0];
  const float* W = (const float*)d_in[1];
  float* P = (float*)d_out;
  float* M = P + (size_t)N_TOK * E_DIM;

  uint4* WF = (uint4*)d_ws;                                 // 768 KB at offset 0
  float* Part = (float*)((char*)d_ws + (size_t)(1 << 20));  // 16 MB at offset 1 MB

  wprep_kernel<<<dim3(64), dim3(256), 0, stream>>>(W, WF);
  gemm_partial<<<dim3(512), dim3(256), 0, stream>>>(X, WF, Part);
  reduce_router<<<dim3(1024), dim3(256), 0, stream>>>(Part, P, M);
}